// Round 1
// baseline (3112.332 us; speedup 1.0000x reference)
//
#include <hip/hip_runtime.h>
#include <hip/hip_bf16.h>

// ---------------- problem constants ----------------
#define BB 32
#define C_IN 3
#define HW 64
#define CL1_F 64
#define V1 1024
#define CL2_F 128
#define CL2_K 16
#define V2 256
#define CL3_F 256
#define CL3_K 16
#define V3 64
#define FC1_IN 16384
#define FC1_F 512
#define FC2_F 10

// ---------------- conv1 (5x5 pad2) + ReLU + 2x2 maxpool ----------------
// P[b][co][p] , p = ph*32+pw  (pooled 32x32)
__global__ __launch_bounds__(256) void conv_pool_k(const float* __restrict__ x,
                                                   const float* __restrict__ w,
                                                   const float* __restrict__ bias,
                                                   float* __restrict__ P) {
  __shared__ float wl[C_IN * 25];
  int n = blockIdx.x * 256 + threadIdx.x;     // b*64*1024 + co*1024 + p
  int p = n & 1023, co = (n >> 10) & 63, b = n >> 16;
  if (threadIdx.x < C_IN * 25) wl[threadIdx.x] = w[co * C_IN * 25 + threadIdx.x];
  __syncthreads();
  int ph = p >> 5, pw = p & 31;
  float m = -1e30f;
  float bv = bias[co];
#pragma unroll
  for (int dy = 0; dy < 2; ++dy)
#pragma unroll
    for (int dx = 0; dx < 2; ++dx) {
      int h = 2 * ph + dy, wq = 2 * pw + dx;
      float acc = bv;
      for (int ci = 0; ci < C_IN; ++ci)
#pragma unroll
        for (int kh = 0; kh < 5; ++kh) {
          int ih = h - 2 + kh;
          if (ih < 0 || ih >= HW) continue;
#pragma unroll
          for (int kw = 0; kw < 5; ++kw) {
            int iw = wq - 2 + kw;
            if (iw < 0 || iw >= HW) continue;
            acc += x[((b * C_IN + ci) * HW + ih) * HW + iw] * wl[(ci * 5 + kh) * 5 + kw];
          }
        }
      m = fmaxf(m, acc);
    }
  P[n] = fmaxf(m, 0.f);
}

// ---------------- BN stats: per-channel mean / rstd over (b, p) ----------------
__global__ __launch_bounds__(256) void bn_stats_k(const float* __restrict__ P,
                                                  float* __restrict__ stats) {
  int c = blockIdx.x;
  float s = 0.f, s2 = 0.f;
  for (int i = threadIdx.x; i < BB * V1; i += 256) {
    int b = i >> 10, p = i & 1023;
    float v = P[((b * 64 + c) << 10) + p];
    s += v; s2 += v * v;
  }
#pragma unroll
  for (int o = 32; o > 0; o >>= 1) { s += __shfl_down(s, o); s2 += __shfl_down(s2, o); }
  __shared__ float sh[2][4];
  int wid = threadIdx.x >> 6;
  if ((threadIdx.x & 63) == 0) { sh[0][wid] = s; sh[1][wid] = s2; }
  __syncthreads();
  if (threadIdx.x == 0) {
    float ts = sh[0][0] + sh[0][1] + sh[0][2] + sh[0][3];
    float ts2 = sh[1][0] + sh[1][1] + sh[1][2] + sh[1][3];
    float mean = ts / (float)(BB * V1);
    float var = ts2 / (float)(BB * V1) - mean * mean;
    stats[c] = mean;
    stats[64 + c] = rsqrtf(var + 1e-5f);
  }
}

// ---------------- gather(node_index, perm) + BN apply + transpose ----------------
// X[v][b*64 + c] = (P[b][c][flat(ni[perm[v]])] - mean[c]) * rstd[c]
__global__ __launch_bounds__(256) void build_x0_k(const float* __restrict__ P,
                                                  const float* __restrict__ stats,
                                                  const int* __restrict__ ni,
                                                  const int* __restrict__ perm,
                                                  float* __restrict__ X) {
  int n = blockIdx.x * 256 + threadIdx.x;  // V1 * 2048
  int col = n & 2047, v = n >> 11;
  int c = col & 63, b = col >> 6;
  int pv = perm[v];
  int q = ni[2 * pv] * 32 + ni[2 * pv + 1];
  float val = P[((b * 64 + c) << 10) + q];
  X[n] = (val - stats[c]) * stats[64 + c];
}

// ---------------- generic tiled fp32 GEMM ----------------
// Y(MxN) = A(MxK) @ B(KxN);  A row-major (lda).  B element (k,n) = Bm[k*ldbk + n*ldbn]
// MODE 0: Y = AB    MODE 1: Y = 2*AB - Y (in-place Chebyshev)    MODE 2: Y += AB
// BVEC: B rows contiguous (ldbn==1) -> vectorized loads
template <int MODE, bool BVEC>
__global__ __launch_bounds__(256) void gemm_f32_k(int M, int N, int Kd,
                                                  const float* __restrict__ A, int lda,
                                                  const float* __restrict__ Bm, int ldbk, int ldbn,
                                                  float* __restrict__ Y) {
  __shared__ float As[16][68];   // padded: write conflicts -> 2-way (free)
  __shared__ float Bs[16][128];
  const int m0 = blockIdx.x * 64, n0 = blockIdx.y * 128;
  const int tid = threadIdx.x;
  const int tx = tid & 15, ty = tid >> 4;
  float acc[4][8] = {};
  for (int k0 = 0; k0 < Kd; k0 += 16) {
    {  // A tile 64x16, one float4 per thread, store transposed
      int r = tid >> 2, kk = (tid & 3) * 4;
      const float4 a4 = *reinterpret_cast<const float4*>(&A[(size_t)(m0 + r) * lda + k0 + kk]);
      As[kk + 0][r] = a4.x; As[kk + 1][r] = a4.y; As[kk + 2][r] = a4.z; As[kk + 3][r] = a4.w;
    }
    if (BVEC) {  // B tile 16x128, two float4 per thread
      int kk = tid >> 4, nn = (tid & 15) * 8;
      const float* bp = &Bm[(size_t)(k0 + kk) * ldbk + n0 + nn];
      *reinterpret_cast<float4*>(&Bs[kk][nn]) = *reinterpret_cast<const float4*>(bp);
      *reinterpret_cast<float4*>(&Bs[kk][nn + 4]) = *reinterpret_cast<const float4*>(bp + 4);
    } else {
      for (int i = tid; i < 2048; i += 256) {
        int kk = i >> 7, nn = i & 127;
        Bs[kk][nn] = Bm[(size_t)(k0 + kk) * ldbk + (size_t)(n0 + nn) * ldbn];
      }
    }
    __syncthreads();
#pragma unroll
    for (int kk = 0; kk < 16; ++kk) {
      float a[4], b[8];
      *reinterpret_cast<float4*>(a) = *reinterpret_cast<const float4*>(&As[kk][ty * 4]);
      *reinterpret_cast<float4*>(b) = *reinterpret_cast<const float4*>(&Bs[kk][tx * 8]);
      *reinterpret_cast<float4*>(b + 4) = *reinterpret_cast<const float4*>(&Bs[kk][tx * 8 + 4]);
#pragma unroll
      for (int i = 0; i < 4; ++i)
#pragma unroll
        for (int j = 0; j < 8; ++j) acc[i][j] += a[i] * b[j];
    }
    __syncthreads();
  }
#pragma unroll
  for (int i = 0; i < 4; ++i) {
    float* yp = &Y[(size_t)(m0 + ty * 4 + i) * N + n0 + tx * 8];
#pragma unroll
    for (int j = 0; j < 8; ++j) {
      if (MODE == 0) yp[j] = acc[i][j];
      else if (MODE == 1) yp[j] = 2.f * acc[i][j] - yp[j];
      else yp[j] += acc[i][j];
    }
  }
}

// ---------------- gc1 epilogue: +bias, ReLU, pool4 over v; emit gc2 chain input ----------------
// X2[v2][b*128 + f] = max_q relu(out1[(4*v2+q)*32 + b][f] + b2[f])
__global__ __launch_bounds__(256) void relu_pool1_k(const float* __restrict__ out1,
                                                    const float* __restrict__ b2,
                                                    float* __restrict__ X2) {
  int n = blockIdx.x * 256 + threadIdx.x;  // 256*4096
  int col = n & 4095, v2 = n >> 12;
  int f = col & 127, b = col >> 7;
  float bb = b2[f];
  float m = -1e30f;
#pragma unroll
  for (int q = 0; q < 4; ++q)
    m = fmaxf(m, out1[(size_t)((4 * v2 + q) * 32 + b) * 128 + f] + bb);
  X2[n] = fmaxf(m, 0.f);
}

// ---------------- gc2 epilogue: +bias, ReLU, pool4; emit fc1 input row-major ----------------
// At[b][c*64 + v3] = max_q relu(out2[(4*v3+q)*32 + b][c] + b3[c])
__global__ __launch_bounds__(256) void relu_pool2_k(const float* __restrict__ out2,
                                                    const float* __restrict__ b3,
                                                    float* __restrict__ At) {
  int n = blockIdx.x * 256 + threadIdx.x;  // 32*16384
  int b = n >> 14, col = n & 16383;
  int c = col >> 6, v3 = col & 63;
  float bb = b3[c];
  float m = -1e30f;
#pragma unroll
  for (int q = 0; q < 4; ++q)
    m = fmaxf(m, out2[(size_t)((4 * v3 + q) * 32 + b) * 256 + c] + bb);
  At[n] = fmaxf(m, 0.f);
}

// ---------------- fc1 split-K partials ----------------
// part[ks][b][j] = sum over k-chunk of At[b][k] * W1[j][k]
__global__ __launch_bounds__(256) void fc1_part_k(const float* __restrict__ At,
                                                  const float* __restrict__ W1,
                                                  float* __restrict__ part) {
  int jt = blockIdx.x, ks = blockIdx.y;
  int tid = threadIdx.x;
  int b = tid & 31, jg = tid >> 5;
  int j0 = jt * 32 + jg * 4;
  float acc[4] = {0.f, 0.f, 0.f, 0.f};
  const float* a = At + (size_t)b * FC1_IN + ks * 1024;
  for (int k = 0; k < 1024; k += 4) {
    float4 a4 = *reinterpret_cast<const float4*>(a + k);
#pragma unroll
    for (int jj = 0; jj < 4; ++jj) {
      const float4 w4 = *reinterpret_cast<const float4*>(&W1[(size_t)(j0 + jj) * FC1_IN + ks * 1024 + k]);
      acc[jj] += a4.x * w4.x + a4.y * w4.y + a4.z * w4.z + a4.w * w4.w;
    }
  }
#pragma unroll
  for (int jj = 0; jj < 4; ++jj) part[((size_t)ks * 32 + b) * 512 + j0 + jj] = acc[jj];
}

__global__ __launch_bounds__(256) void fc1_combine_k(const float* __restrict__ part,
                                                     const float* __restrict__ b1,
                                                     float* __restrict__ h) {
  int n = blockIdx.x * 256 + threadIdx.x;  // 32*512
  int b = n >> 9, j = n & 511;
  float s = b1[j];
#pragma unroll
  for (int ks = 0; ks < 16; ++ks) s += part[((size_t)ks * 32 + b) * 512 + j];
  h[n] = fmaxf(s, 0.f);
}

__global__ __launch_bounds__(64) void fc2_k(const float* __restrict__ h,
                                            const float* __restrict__ W2,
                                            const float* __restrict__ b2f,
                                            float* __restrict__ out) {
  int n = blockIdx.x * 64 + threadIdx.x;  // 5*64 = 320
  int b = n / 10, o = n % 10;
  float s = b2f[o];
  const float* hp = h + b * 512;
  const float* wp = W2 + o * 512;
  for (int j = 0; j < 512; ++j) s += hp[j] * wp[j];
  out[n] = s;
}

// ---------------- launch ----------------
extern "C" void kernel_launch(void* const* d_in, const int* in_sizes, int n_in,
                              void* d_out, int out_size, void* d_ws, size_t ws_size,
                              hipStream_t stream) {
  const float* x      = (const float*)d_in[0];
  const float* conv1w = (const float*)d_in[1];
  const float* conv1b = (const float*)d_in[2];
  const float* L1     = (const float*)d_in[3];
  const float* L2     = (const float*)d_in[4];
  const int*   ni     = (const int*)d_in[5];
  const int*   perm   = (const int*)d_in[6];
  const float* k2w    = (const float*)d_in[7];
  const float* k2b    = (const float*)d_in[8];
  const float* k3w    = (const float*)d_in[9];
  const float* k3b    = (const float*)d_in[10];
  const float* fc1w   = (const float*)d_in[11];
  const float* fc1b   = (const float*)d_in[12];
  const float* fc2w   = (const float*)d_in[13];
  const float* fc2b   = (const float*)d_in[14];
  float* out = (float*)d_out;

  // workspace layout (floats). Lifetimes overlap-safe.
  float* ws = (float*)d_ws;
  const size_t M1 = 2u * 1024 * 1024;          // 2M floats = 8MB
  float* POOLED = ws;                          // [2M]  conv output; dead after build_x0
  float* OUT2   = ws;                          //        reuse for gc2 accumulator (2M)
  float* STATS  = ws + M1;                     // [256]
  float* BUFA   = ws + M1 + 256;               // [2M] gc1 chain ping
  float* X2A    = BUFA;                        //        reuse: gc2 chain ping (1M)
  float* X2B    = BUFA + 1024 * 1024;          //        reuse: gc2 chain pong (1M)
  float* BUFB   = BUFA + M1;                   // [2M] gc1 chain pong
  float* AT     = BUFB;                        //        reuse: fc1 input (512K)
  float* PART   = BUFB + 524288;               //        reuse: fc1 partials (256K)
  float* H      = PART + 262144;               //        reuse: fc1 output (16K)
  float* OUT1   = BUFB + M1;                   // [4M] gc1 accumulator (16MB)

  // 1) conv + relu + pool
  conv_pool_k<<<8192, 256, 0, stream>>>(x, conv1w, conv1b, POOLED);
  // 2) BN stats
  bn_stats_k<<<64, 256, 0, stream>>>(POOLED, STATS);
  // 3) gather + normalize + transpose -> x0 (V1 x 2048), layout [v][b*64+c]
  build_x0_k<<<8192, 256, 0, stream>>>(POOLED, STATS, ni, perm, BUFA);

  // zero gc1 accumulator
  hipMemsetAsync(OUT1, 0, (size_t)BB * V1 * CL2_F * sizeof(float), stream);

  // gc1: out1[(v*32+b)][f] += sum_c x_k[v][b*64+c] * k2w[f][c*16+k]
  // accum GEMM: M=32768, N=128, K=64; A = x_k (lda=64); B(c,f)=k2w + k, ldbk=16, ldbn=1024
  dim3 gAcc1(512, 1), gChain1(16, 16);
  gemm_f32_k<2, false><<<gAcc1, 256, 0, stream>>>(BB * V1, CL2_F, CL1_F, BUFA, CL1_F,
                                                  k2w + 0, CL2_K, CL1_F * CL2_K, OUT1);
  // x1 = L1 @ x0
  gemm_f32_k<0, true><<<gChain1, 256, 0, stream>>>(V1, 2048, V1, L1, V1, BUFA, 2048, 1, BUFB);
  gemm_f32_k<2, false><<<gAcc1, 256, 0, stream>>>(BB * V1, CL2_F, CL1_F, BUFB, CL1_F,
                                                  k2w + 1, CL2_K, CL1_F * CL2_K, OUT1);
  {
    float* xm2 = BUFA; float* xm1 = BUFB;
    for (int k = 2; k < CL2_K; ++k) {
      // x_k = 2*L1@x_{k-1} - x_{k-2}  (written in-place over x_{k-2})
      gemm_f32_k<1, true><<<gChain1, 256, 0, stream>>>(V1, 2048, V1, L1, V1, xm1, 2048, 1, xm2);
      gemm_f32_k<2, false><<<gAcc1, 256, 0, stream>>>(BB * V1, CL2_F, CL1_F, xm2, CL1_F,
                                                      k2w + k, CL2_K, CL1_F * CL2_K, OUT1);
      float* t = xm2; xm2 = xm1; xm1 = t;
    }
  }

  // gc1 epilogue -> gc2 chain input X2A  (BUFA/BUFB dead now)
  relu_pool1_k<<<4096, 256, 0, stream>>>(OUT1, k2b, X2A);

  // zero gc2 accumulator (POOLED dead)
  hipMemsetAsync(OUT2, 0, (size_t)BB * V2 * CL3_F * sizeof(float), stream);

  dim3 gAcc2(128, 2), gChain2(4, 32);
  gemm_f32_k<2, false><<<gAcc2, 256, 0, stream>>>(BB * V2, CL3_F, CL2_F, X2A, CL2_F,
                                                  k3w + 0, CL3_K, CL2_F * CL3_K, OUT2);
  gemm_f32_k<0, true><<<gChain2, 256, 0, stream>>>(V2, 4096, V2, L2, V2, X2A, 4096, 1, X2B);
  gemm_f32_k<2, false><<<gAcc2, 256, 0, stream>>>(BB * V2, CL3_F, CL2_F, X2B, CL2_F,
                                                  k3w + 1, CL3_K, CL2_F * CL3_K, OUT2);
  {
    float* xm2 = X2A; float* xm1 = X2B;
    for (int k = 2; k < CL3_K; ++k) {
      gemm_f32_k<1, true><<<gChain2, 256, 0, stream>>>(V2, 4096, V2, L2, V2, xm1, 4096, 1, xm2);
      gemm_f32_k<2, false><<<gAcc2, 256, 0, stream>>>(BB * V2, CL3_F, CL2_F, xm2, CL2_F,
                                                      k3w + k, CL3_K, CL2_F * CL3_K, OUT2);
      float* t = xm2; xm2 = xm1; xm1 = t;
    }
  }

  // gc2 epilogue -> fc1 input At[b][c*64+v3]  (BUFB region reused)
  relu_pool2_k<<<2048, 256, 0, stream>>>(OUT2, k3b, AT);

  // fc1 (split-K=16) + relu
  dim3 gFc1(16, 16);
  fc1_part_k<<<gFc1, 256, 0, stream>>>(AT, fc1w, PART);
  fc1_combine_k<<<64, 256, 0, stream>>>(PART, fc1b, H);
  // fc2
  fc2_k<<<5, 64, 0, stream>>>(H, fc2w, fc2b, out);
}

// Round 2
// 1575.300 us; speedup vs baseline: 1.9757x; 1.9757x over previous
//
#include <hip/hip_runtime.h>
#include <hip/hip_bf16.h>

// ---------------- problem constants ----------------
#define BB 32
#define C_IN 3
#define HW 64
#define CL1_F 64
#define V1 1024
#define CL2_F 128
#define CL2_K 16
#define V2 256
#define CL3_F 256
#define CL3_K 16
#define V3 64
#define FC1_IN 16384
#define FC1_F 512
#define FC2_F 10

typedef __attribute__((ext_vector_type(8))) short bf16x8;
typedef __attribute__((ext_vector_type(8))) unsigned short u16x8;
typedef __attribute__((ext_vector_type(4))) float f32x4;

__device__ __forceinline__ float bfu2f(unsigned short u) {
  union { unsigned int i; float f; } x; x.i = ((unsigned)u) << 16; return x.f;
}
__device__ __forceinline__ unsigned short f2bf(float v) {
  union { float f; unsigned int i; } x; x.f = v;
  unsigned r = x.i + 0x7FFFu + ((x.i >> 16) & 1u);
  return (unsigned short)(r >> 16);
}

// ---------------- conv1 (5x5 pad2) + ReLU + 2x2 maxpool ----------------
// block = (b, ph); P[b][co][ph*32+pw]
__global__ __launch_bounds__(256) void conv_pool_k(const float* __restrict__ x,
                                                   const float* __restrict__ w,
                                                   const float* __restrict__ bias,
                                                   float* __restrict__ P) {
  __shared__ float xs[3][7][72];
  __shared__ float wl[64][76];
  const int b = blockIdx.x >> 5, ph = blockIdx.x & 31;
  const int t = threadIdx.x;
  for (int i = t; i < 64 * 75; i += 256) wl[i / 75][i % 75] = w[i];
  for (int i = t; i < 3 * 7 * 72; i += 256) {
    int col = i % 72, rr = (i / 72) % 7, ci = i / (72 * 7);
    int ih = 2 * ph - 2 + rr, iw = col - 2;
    float v = 0.f;
    if (ih >= 0 && ih < HW && iw >= 0 && iw < HW)
      v = x[((b * 3 + ci) * HW + ih) * HW + iw];
    xs[ci][rr][col] = v;
  }
  __syncthreads();
  const int co = t >> 2, pq = t & 3;
  float acc[8][2][2];
#pragma unroll
  for (int i = 0; i < 8; ++i)
#pragma unroll
    for (int a = 0; a < 2; ++a)
#pragma unroll
      for (int d = 0; d < 2; ++d) acc[i][a][d] = 0.f;

  for (int ci = 0; ci < 3; ++ci) {
#pragma unroll
    for (int kh = 0; kh < 5; ++kh) {
      float w5[5];
#pragma unroll
      for (int j = 0; j < 5; ++j) w5[j] = wl[co][ci * 25 + kh * 5 + j];
#pragma unroll
      for (int dy = 0; dy < 2; ++dy) {
        const int r = kh + dy;
        float in[20];
#pragma unroll
        for (int q4 = 0; q4 < 5; ++q4) {
          float4 v4 = *(const float4*)&xs[ci][r][16 * pq + q4 * 4];
          in[q4 * 4 + 0] = v4.x; in[q4 * 4 + 1] = v4.y;
          in[q4 * 4 + 2] = v4.z; in[q4 * 4 + 3] = v4.w;
        }
#pragma unroll
        for (int i = 0; i < 8; ++i)
#pragma unroll
          for (int dx = 0; dx < 2; ++dx)
#pragma unroll
            for (int kw = 0; kw < 5; ++kw)
              acc[i][dy][dx] += w5[kw] * in[2 * i + dx + kw];
      }
    }
  }
  const float bv = bias[co];
#pragma unroll
  for (int i = 0; i < 8; ++i) {
    float m = fmaxf(fmaxf(acc[i][0][0], acc[i][0][1]), fmaxf(acc[i][1][0], acc[i][1][1]));
    P[((size_t)(b * 64 + co) << 10) + (ph << 5) + pq * 8 + i] = fmaxf(m + bv, 0.f);
  }
}

// ---------------- BN stats ----------------
__global__ __launch_bounds__(256) void bn_stats_k(const float* __restrict__ P,
                                                  float* __restrict__ stats) {
  int c = blockIdx.x;
  float s = 0.f, s2 = 0.f;
  for (int i = threadIdx.x; i < BB * V1; i += 256) {
    int b = i >> 10, p = i & 1023;
    float v = P[((size_t)(b * 64 + c) << 10) + p];
    s += v; s2 += v * v;
  }
#pragma unroll
  for (int o = 32; o > 0; o >>= 1) { s += __shfl_down(s, o); s2 += __shfl_down(s2, o); }
  __shared__ float sh[2][4];
  int wid = threadIdx.x >> 6;
  if ((threadIdx.x & 63) == 0) { sh[0][wid] = s; sh[1][wid] = s2; }
  __syncthreads();
  if (threadIdx.x == 0) {
    float ts = sh[0][0] + sh[0][1] + sh[0][2] + sh[0][3];
    float ts2 = sh[1][0] + sh[1][1] + sh[1][2] + sh[1][3];
    float mean = ts / (float)(BB * V1);
    float var = ts2 / (float)(BB * V1) - mean * mean;
    stats[c] = mean;
    stats[64 + c] = rsqrtf(var + 1e-5f);
  }
}

// ---------------- gather + BN apply -> PG pair layout ----------------
// pair element (col, v): offset ((v>>3)*Mld + col)*8 + (v&7)
__global__ __launch_bounds__(256) void build_x0_k(const float* __restrict__ P,
                                                  const float* __restrict__ stats,
                                                  const int* __restrict__ ni,
                                                  const int* __restrict__ perm,
                                                  unsigned short* __restrict__ Xh,
                                                  unsigned short* __restrict__ Xl) {
  int n = blockIdx.x * 256 + threadIdx.x;  // 2048*1024
  int vlow = n & 7, col = (n >> 3) & 2047, vhigh = n >> 14;
  int v = vhigh * 8 + vlow;
  int c = col & 63, b = col >> 6;
  int pv = perm[v];
  int q = ni[2 * pv] * 32 + ni[2 * pv + 1];
  float val = (P[((size_t)(b * 64 + c) << 10) + q] - stats[c]) * stats[64 + c];
  size_t g = ((size_t)(v >> 3) * 2048 + col) * 8 + (v & 7);
  unsigned short h = f2bf(val);
  Xh[g] = h;
  Xl[g] = f2bf(val - bfu2f(h));
}

// ---------------- W reorder: Wr[kq][c][f] = W[f][c*16+kq] ----------------
__global__ __launch_bounds__(256) void wr_prep_k(const float* __restrict__ W,
                                                 float* __restrict__ Wr,
                                                 int Cc, int Nf) {
  int d = blockIdx.x * 256 + threadIdx.x;  // 16*Cc*Nf
  int f = d % Nf;
  int c = (d / Nf) % Cc;
  int kq = d / (Nf * Cc);
  Wr[d] = W[(size_t)f * (Cc * 16) + c * 16 + kq];
}

// ---------------- Chebyshev step: MFMA bf16 3-product split ----------------
// new^T[col][v] = sum_u (Ah+Al)[col][u] * L[u][v]  (L symmetric; B staged from L rows)
// MODE 0: out = D ; MODE 1: out = 2D - (Ph+Pl), written in-place over (Ph,Pl)
template <int TM, int MODE>
__global__ __launch_bounds__(256) void cheb_step_k(
    int Mld, int Kd,
    const unsigned short* __restrict__ Ah, const unsigned short* __restrict__ Al,
    const float* __restrict__ Lf,
    unsigned short* __restrict__ Ph, unsigned short* __restrict__ Pl) {
  constexpr int FN = (TM == 64) ? 2 : 1;
  __shared__ unsigned short sAh[8 * TM * 8];
  __shared__ unsigned short sAl[8 * TM * 8];
  __shared__ unsigned short sBh[8 * 64 * 8];
  __shared__ unsigned short sBl[8 * 64 * 8];
  const int m0 = blockIdx.x * TM, n0 = blockIdx.y * 64;
  const int t = threadIdx.x;
  const int lane = t & 63, wid = t >> 6;
  const int wm0 = (TM == 64) ? (wid >> 1) * 32 : 0;
  const int wn0 = (TM == 64) ? (wid & 1) * 32 : wid * 16;
  f32x4 acc[2][FN];
#pragma unroll
  for (int a = 0; a < 2; ++a)
#pragma unroll
    for (int c = 0; c < FN; ++c) acc[a][c] = (f32x4){0.f, 0.f, 0.f, 0.f};

  for (int k0 = 0; k0 < Kd; k0 += 64) {
    __syncthreads();
    // stage A pair (already bf16, PG layout: 16B per (slot,m))
    for (int idx = t; idx < TM * 8; idx += 256) {
      int m = idx & (TM - 1), slot = idx / TM;
      size_t g = ((size_t)((k0 >> 3) + slot) * Mld + (m0 + m)) * 8;
      *(uint4*)&sAh[(slot * TM + m) * 8] = *(const uint4*)&Ah[g];
      *(uint4*)&sAl[(slot * TM + m) * 8] = *(const uint4*)&Al[g];
    }
    // stage B from fp32 L rows (symmetry), split on the fly
    for (int idx = t; idx < 64 * 8; idx += 256) {
      int n = idx & 63, slot = idx >> 6;
      const float* src = &Lf[(size_t)(n0 + n) * Kd + k0 + slot * 8];
      float4 f0 = *(const float4*)src;
      float4 f1 = *(const float4*)(src + 4);
      float vv[8] = {f0.x, f0.y, f0.z, f0.w, f1.x, f1.y, f1.z, f1.w};
      u16x8 h8, l8;
#pragma unroll
      for (int j = 0; j < 8; ++j) {
        unsigned short h = f2bf(vv[j]);
        h8[j] = h;
        l8[j] = f2bf(vv[j] - bfu2f(h));
      }
      *(u16x8*)&sBh[(slot * 64 + n) * 8] = h8;
      *(u16x8*)&sBl[(slot * 64 + n) * 8] = l8;
    }
    __syncthreads();
#pragma unroll
    for (int ks = 0; ks < 2; ++ks) {
      const int srow = ks * 4 + (lane >> 4);
      const int ar = wm0 + (lane & 15);
      const int br = wn0 + (lane & 15);
      bf16x8 ah0 = *(const bf16x8*)&sAh[(srow * TM + ar) * 8];
      bf16x8 ah1 = *(const bf16x8*)&sAh[(srow * TM + ar + 16) * 8];
      bf16x8 al0 = *(const bf16x8*)&sAl[(srow * TM + ar) * 8];
      bf16x8 al1 = *(const bf16x8*)&sAl[(srow * TM + ar + 16) * 8];
      bf16x8 bh0 = *(const bf16x8*)&sBh[(srow * 64 + br) * 8];
      bf16x8 bl0 = *(const bf16x8*)&sBl[(srow * 64 + br) * 8];
      acc[0][0] = __builtin_amdgcn_mfma_f32_16x16x32_bf16(ah0, bh0, acc[0][0], 0, 0, 0);
      acc[0][0] = __builtin_amdgcn_mfma_f32_16x16x32_bf16(al0, bh0, acc[0][0], 0, 0, 0);
      acc[0][0] = __builtin_amdgcn_mfma_f32_16x16x32_bf16(ah0, bl0, acc[0][0], 0, 0, 0);
      acc[1][0] = __builtin_amdgcn_mfma_f32_16x16x32_bf16(ah1, bh0, acc[1][0], 0, 0, 0);
      acc[1][0] = __builtin_amdgcn_mfma_f32_16x16x32_bf16(al1, bh0, acc[1][0], 0, 0, 0);
      acc[1][0] = __builtin_amdgcn_mfma_f32_16x16x32_bf16(ah1, bl0, acc[1][0], 0, 0, 0);
      if constexpr (FN == 2) {
        bf16x8 bh1 = *(const bf16x8*)&sBh[(srow * 64 + br + 16) * 8];
        bf16x8 bl1 = *(const bf16x8*)&sBl[(srow * 64 + br + 16) * 8];
        acc[0][1] = __builtin_amdgcn_mfma_f32_16x16x32_bf16(ah0, bh1, acc[0][1], 0, 0, 0);
        acc[0][1] = __builtin_amdgcn_mfma_f32_16x16x32_bf16(al0, bh1, acc[0][1], 0, 0, 0);
        acc[0][1] = __builtin_amdgcn_mfma_f32_16x16x32_bf16(ah0, bl1, acc[0][1], 0, 0, 0);
        acc[1][1] = __builtin_amdgcn_mfma_f32_16x16x32_bf16(ah1, bh1, acc[1][1], 0, 0, 0);
        acc[1][1] = __builtin_amdgcn_mfma_f32_16x16x32_bf16(al1, bh1, acc[1][1], 0, 0, 0);
        acc[1][1] = __builtin_amdgcn_mfma_f32_16x16x32_bf16(ah1, bl1, acc[1][1], 0, 0, 0);
      }
    }
  }
  // epilogue: fused Chebyshev combine, write new (hi,lo) pair
#pragma unroll
  for (int fm = 0; fm < 2; ++fm)
#pragma unroll
    for (int fn = 0; fn < FN; ++fn)
#pragma unroll
      for (int j = 0; j < 4; ++j) {
        int gm = m0 + wm0 + fm * 16 + ((lane >> 4) * 4 + j);
        int gn = n0 + wn0 + fn * 16 + (lane & 15);
        size_t g = ((size_t)(gn >> 3) * Mld + gm) * 8 + (gn & 7);
        float d = acc[fm][fn][j];
        float nv;
        if (MODE == 0) nv = d;
        else nv = 2.f * d - (bfu2f(Ph[g]) + bfu2f(Pl[g]));
        unsigned short h = f2bf(nv);
        Ph[g] = h;
        Pl[g] = f2bf(nv - bfu2f(h));
      }
}

// ---------------- weight apply (fp32 VALU), 2 Chebyshev terms per dispatch ----------------
// OUT[b*V + v][f] += sum_{t in 0..1, c} (pair_t reconstructed) * Wr[(kq0+t)][c][f]
template <int CC, int NF>
__global__ __launch_bounds__(256) void wapply_k(
    int V, int Mld,
    const unsigned short* __restrict__ XAh, const unsigned short* __restrict__ XAl,
    const unsigned short* __restrict__ XBh, const unsigned short* __restrict__ XBl,
    const float* __restrict__ Wr, int kq0,
    float* __restrict__ OUT) {
  __shared__ float As[16][68];
  __shared__ float Bs[16][128];
  const int m0 = blockIdx.x * 64;
  const int n0 = blockIdx.y * 128;
  const int b = m0 / V, v0 = m0 % V;
  const int t = threadIdx.x;
  const int tx = t & 15, ty = t >> 4;
  float acc[4][8] = {};
  const int Kd = 2 * CC;
  for (int k0 = 0; k0 < Kd; k0 += 16) {
    for (int idx = t; idx < 1024; idx += 256) {
      int kk = idx >> 6, dv = idx & 63;
      int kg = k0 + kk;
      int c = kg & (CC - 1);
      int v = v0 + dv;
      int col = b * CC + c;
      size_t g = ((size_t)(v >> 3) * Mld + col) * 8 + (v & 7);
      float val;
      if (kg < CC) val = bfu2f(XAh[g]) + bfu2f(XAl[g]);
      else val = bfu2f(XBh[g]) + bfu2f(XBl[g]);
      As[kk][dv] = val;
    }
    for (int idx = t; idx < 2048; idx += 256) {
      int kk = idx >> 7, ff = idx & 127;
      int kg = k0 + kk;
      int c = kg & (CC - 1);
      int tt = (kg < CC) ? 0 : 1;
      Bs[kk][ff] = Wr[(size_t)(kq0 + tt) * (CC * NF) + c * NF + (n0 + ff)];
    }
    __syncthreads();
#pragma unroll
    for (int kk = 0; kk < 16; ++kk) {
      float a[4], bb[8];
      *reinterpret_cast<float4*>(a) = *reinterpret_cast<const float4*>(&As[kk][ty * 4]);
      *reinterpret_cast<float4*>(bb) = *reinterpret_cast<const float4*>(&Bs[kk][tx * 8]);
      *reinterpret_cast<float4*>(bb + 4) = *reinterpret_cast<const float4*>(&Bs[kk][tx * 8 + 4]);
#pragma unroll
      for (int i = 0; i < 4; ++i)
#pragma unroll
        for (int j = 0; j < 8; ++j) acc[i][j] += a[i] * bb[j];
    }
    __syncthreads();
  }
#pragma unroll
  for (int i = 0; i < 4; ++i) {
    float* yp = &OUT[(size_t)(m0 + ty * 4 + i) * NF + n0 + tx * 8];
#pragma unroll
    for (int j = 0; j < 8; ++j) yp[j] += acc[i][j];
  }
}

// ---------------- gc1 epilogue: +bias, relu, pool4 -> pairs2 PG layout ----------------
__global__ __launch_bounds__(256) void relu_pool1_k(const float* __restrict__ OUT1,
                                                    const float* __restrict__ b2,
                                                    unsigned short* __restrict__ Xh,
                                                    unsigned short* __restrict__ Xl) {
  int n = blockIdx.x * 256 + threadIdx.x;  // 256 v2 * 4096 col2
  int v2 = n >> 12, col2 = n & 4095;
  int b = col2 >> 7, f = col2 & 127;
  float bb = b2[f];
  float m = -1e30f;
#pragma unroll
  for (int q = 0; q < 4; ++q)
    m = fmaxf(m, OUT1[(size_t)((b << 10) + 4 * v2 + q) * 128 + f] + bb);
  float val = fmaxf(m, 0.f);
  size_t g = ((size_t)(v2 >> 3) * 4096 + col2) * 8 + (v2 & 7);
  unsigned short h = f2bf(val);
  Xh[g] = h;
  Xl[g] = f2bf(val - bfu2f(h));
}

// ---------------- gc2 epilogue: +bias, relu, pool4 -> At[b][c*64+v3] fp32 ----------------
__global__ __launch_bounds__(256) void relu_pool2_k(const float* __restrict__ OUT2,
                                                    const float* __restrict__ b3,
                                                    float* __restrict__ At) {
  int n = blockIdx.x * 256 + threadIdx.x;  // 32*64*256: c fast
  int c = n & 255, v3 = (n >> 8) & 63, b = n >> 14;
  float bb = b3[c];
  float m = -1e30f;
#pragma unroll
  for (int q = 0; q < 4; ++q)
    m = fmaxf(m, OUT2[(size_t)((b << 8) + 4 * v3 + q) * 256 + c] + bb);
  At[(size_t)b * FC1_IN + c * 64 + v3] = fmaxf(m, 0.f);
}

// ---------------- fc1 split-K ----------------
__global__ __launch_bounds__(256) void fc1_part_k(const float* __restrict__ At,
                                                  const float* __restrict__ W1,
                                                  float* __restrict__ part) {
  int jt = blockIdx.x, ks = blockIdx.y;
  int tid = threadIdx.x;
  int b = tid & 31, jg = tid >> 5;
  int j0 = jt * 32 + jg * 4;
  float acc[4] = {0.f, 0.f, 0.f, 0.f};
  const float* a = At + (size_t)b * FC1_IN + ks * 1024;
  for (int k = 0; k < 1024; k += 4) {
    float4 a4 = *reinterpret_cast<const float4*>(a + k);
#pragma unroll
    for (int jj = 0; jj < 4; ++jj) {
      const float4 w4 = *reinterpret_cast<const float4*>(&W1[(size_t)(j0 + jj) * FC1_IN + ks * 1024 + k]);
      acc[jj] += a4.x * w4.x + a4.y * w4.y + a4.z * w4.z + a4.w * w4.w;
    }
  }
#pragma unroll
  for (int jj = 0; jj < 4; ++jj) part[((size_t)ks * 32 + b) * 512 + j0 + jj] = acc[jj];
}

__global__ __launch_bounds__(256) void fc1_combine_k(const float* __restrict__ part,
                                                     const float* __restrict__ b1,
                                                     float* __restrict__ h) {
  int n = blockIdx.x * 256 + threadIdx.x;  // 32*512
  int b = n >> 9, j = n & 511;
  float s = b1[j];
#pragma unroll
  for (int ks = 0; ks < 16; ++ks) s += part[((size_t)ks * 32 + b) * 512 + j];
  h[n] = fmaxf(s, 0.f);
}

__global__ __launch_bounds__(64) void fc2_k(const float* __restrict__ h,
                                            const float* __restrict__ W2,
                                            const float* __restrict__ b2f,
                                            float* __restrict__ out) {
  int n = blockIdx.x * 64 + threadIdx.x;  // 320
  int b = n / 10, o = n % 10;
  float s = b2f[o];
  const float* hp = h + b * 512;
  const float* wp = W2 + o * 512;
  for (int j = 0; j < 512; ++j) s += hp[j] * wp[j];
  out[n] = s;
}

// ---------------- launch ----------------
extern "C" void kernel_launch(void* const* d_in, const int* in_sizes, int n_in,
                              void* d_out, int out_size, void* d_ws, size_t ws_size,
                              hipStream_t stream) {
  const float* x      = (const float*)d_in[0];
  const float* conv1w = (const float*)d_in[1];
  const float* conv1b = (const float*)d_in[2];
  const float* L1     = (const float*)d_in[3];
  const float* L2     = (const float*)d_in[4];
  const int*   ni     = (const int*)d_in[5];
  const int*   perm   = (const int*)d_in[6];
  const float* k2w    = (const float*)d_in[7];
  const float* k2b    = (const float*)d_in[8];
  const float* k3w    = (const float*)d_in[9];
  const float* k3b    = (const float*)d_in[10];
  const float* fc1w   = (const float*)d_in[11];
  const float* fc1b   = (const float*)d_in[12];
  const float* fc2w   = (const float*)d_in[13];
  const float* fc2b   = (const float*)d_in[14];
  float* out = (float*)d_out;

  char* ws = (char*)d_ws;
  const size_t MB = 1024 * 1024;
  // phase A
  float* P     = (float*)(ws + 0);            // 8MB
  float* STATS = (float*)(ws + 37 * MB);      // 512B (inside QL1, dead by x1)
  // persistent phase B
  unsigned short* PH1 = (unsigned short*)(ws + 24 * MB);  // 4MB each
  unsigned short* PL1 = (unsigned short*)(ws + 28 * MB);
  unsigned short* QH1 = (unsigned short*)(ws + 32 * MB);
  unsigned short* QL1 = (unsigned short*)(ws + 36 * MB);
  float* WR1  = (float*)(ws + 0);             // 512KB, after P dead
  float* OUT1 = (float*)(ws + 8 * MB);        // 16MB
  // phase C overlays
  unsigned short* P2PH = (unsigned short*)(ws + 0);       // 2MB each
  unsigned short* P2PL = (unsigned short*)(ws + 2 * MB);
  unsigned short* P2QH = (unsigned short*)(ws + 4 * MB);
  unsigned short* P2QL = (unsigned short*)(ws + 6 * MB);
  float* OUT2 = (float*)(ws + 8 * MB);        // 8MB (over OUT1 low half, after dead)
  float* AT   = (float*)(ws + 16 * MB);       // 2MB
  float* PART = (float*)(ws + 18 * MB);       // 1MB
  float* H    = (float*)(ws + 19 * MB);       // 64KB
  float* WR2  = (float*)(ws + 20 * MB);       // 2MB

  // ---- phase A ----
  conv_pool_k<<<1024, 256, 0, stream>>>(x, conv1w, conv1b, P);
  bn_stats_k<<<64, 256, 0, stream>>>(P, STATS);
  build_x0_k<<<8192, 256, 0, stream>>>(P, STATS, ni, perm, PH1, PL1);
  wr_prep_k<<<512, 256, 0, stream>>>(k2w, WR1, 64, 128);   // P dead now
  hipMemsetAsync(OUT1, 0, (size_t)BB * V1 * CL2_F * sizeof(float), stream);

  // ---- phase B: gc1 ----
  // x1 = L1 x0
  cheb_step_k<64, 0><<<dim3(32, 16), 256, 0, stream>>>(2048, 1024, PH1, PL1, L1, QH1, QL1);
  wapply_k<64, 128><<<dim3(512, 1), 256, 0, stream>>>(1024, 2048, PH1, PL1, QH1, QL1, WR1, 0, OUT1);
  {
    unsigned short *ah = QH1, *al = QL1, *ph = PH1, *pl = PL1;
    for (int k = 2; k < CL2_K; ++k) {
      cheb_step_k<64, 1><<<dim3(32, 16), 256, 0, stream>>>(2048, 1024, ah, al, L1, ph, pl);
      // now (ph,pl)=x_k, (ah,al)=x_{k-1}
      if (k & 1)
        wapply_k<64, 128><<<dim3(512, 1), 256, 0, stream>>>(1024, 2048, ah, al, ph, pl, WR1, k - 1, OUT1);
      unsigned short* t1 = ah; ah = ph; ph = t1;
      unsigned short* t2 = al; al = pl; pl = t2;
    }
  }
  relu_pool1_k<<<4096, 256, 0, stream>>>(OUT1, k2b, P2PH, P2PL);

  // ---- phase C: gc2 ----
  wr_prep_k<<<2048, 256, 0, stream>>>(k3w, WR2, 128, 256);  // OUT1 dead
  hipMemsetAsync(OUT2, 0, (size_t)BB * V2 * CL3_F * sizeof(float), stream);
  cheb_step_k<32, 0><<<dim3(128, 4), 256, 0, stream>>>(4096, 256, P2PH, P2PL, L2, P2QH, P2QL);
  wapply_k<128, 256><<<dim3(128, 2), 256, 0, stream>>>(256, 4096, P2PH, P2PL, P2QH, P2QL, WR2, 0, OUT2);
  {
    unsigned short *ah = P2QH, *al = P2QL, *ph = P2PH, *pl = P2PL;
    for (int k = 2; k < CL3_K; ++k) {
      cheb_step_k<32, 1><<<dim3(128, 4), 256, 0, stream>>>(4096, 256, ah, al, L2, ph, pl);
      if (k & 1)
        wapply_k<128, 256><<<dim3(128, 2), 256, 0, stream>>>(256, 4096, ah, al, ph, pl, WR2, k - 1, OUT2);
      unsigned short* t1 = ah; ah = ph; ph = t1;
      unsigned short* t2 = al; al = pl; pl = t2;
    }
  }
  relu_pool2_k<<<2048, 256, 0, stream>>>(OUT2, k3b, AT);

  // ---- fc ----
  dim3 gFc1(16, 16);
  fc1_part_k<<<gFc1, 256, 0, stream>>>(AT, fc1w, PART);
  fc1_combine_k<<<64, 256, 0, stream>>>(PART, fc1b, H);
  fc2_k<<<5, 64, 0, stream>>>(H, fc2w, fc2b, out);
}

// Round 3
// 960.268 us; speedup vs baseline: 3.2411x; 1.6405x over previous
//
#include <hip/hip_runtime.h>
#include <hip/hip_bf16.h>

// ---------------- problem constants ----------------
#define BB 32
#define C_IN 3
#define HW 64
#define V1 1024
#define CL2_F 128
#define V2 256
#define CL3_F 256
#define FC1_IN 16384

typedef unsigned short ushortT;
typedef __attribute__((ext_vector_type(8))) short bf16x8;
typedef __attribute__((ext_vector_type(8))) unsigned short u16x8;
typedef __attribute__((ext_vector_type(4))) float f32x4;

__device__ __forceinline__ float bfu2f(unsigned short u) {
  union { unsigned int i; float f; } x; x.i = ((unsigned)u) << 16; return x.f;
}
__device__ __forceinline__ unsigned short f2bf(float v) {
  union { float f; unsigned int i; } x; x.f = v;
  unsigned r = x.i + 0x7FFFu + ((x.i >> 16) & 1u);
  return (unsigned short)(r >> 16);
}

// ---------------- conv1 (5x5 pad2) + ReLU + 2x2 maxpool ----------------
__global__ __launch_bounds__(256) void conv_pool_k(const float* __restrict__ x,
                                                   const float* __restrict__ w,
                                                   const float* __restrict__ bias,
                                                   float* __restrict__ P) {
  __shared__ float xs[3][7][72];
  __shared__ float wl[64][76];
  const int b = blockIdx.x >> 5, ph = blockIdx.x & 31;
  const int t = threadIdx.x;
  for (int i = t; i < 64 * 75; i += 256) wl[i / 75][i % 75] = w[i];
  for (int i = t; i < 3 * 7 * 72; i += 256) {
    int col = i % 72, rr = (i / 72) % 7, ci = i / (72 * 7);
    int ih = 2 * ph - 2 + rr, iw = col - 2;
    float v = 0.f;
    if (ih >= 0 && ih < HW && iw >= 0 && iw < HW)
      v = x[((b * 3 + ci) * HW + ih) * HW + iw];
    xs[ci][rr][col] = v;
  }
  __syncthreads();
  const int co = t >> 2, pq = t & 3;
  float acc[8][2][2];
#pragma unroll
  for (int i = 0; i < 8; ++i)
#pragma unroll
    for (int a = 0; a < 2; ++a)
#pragma unroll
      for (int d = 0; d < 2; ++d) acc[i][a][d] = 0.f;
  for (int ci = 0; ci < 3; ++ci) {
#pragma unroll
    for (int kh = 0; kh < 5; ++kh) {
      float w5[5];
#pragma unroll
      for (int j = 0; j < 5; ++j) w5[j] = wl[co][ci * 25 + kh * 5 + j];
#pragma unroll
      for (int dy = 0; dy < 2; ++dy) {
        const int r = kh + dy;
        float in[20];
#pragma unroll
        for (int q4 = 0; q4 < 5; ++q4) {
          float4 v4 = *(const float4*)&xs[ci][r][16 * pq + q4 * 4];
          in[q4 * 4 + 0] = v4.x; in[q4 * 4 + 1] = v4.y;
          in[q4 * 4 + 2] = v4.z; in[q4 * 4 + 3] = v4.w;
        }
#pragma unroll
        for (int i = 0; i < 8; ++i)
#pragma unroll
          for (int dx = 0; dx < 2; ++dx)
#pragma unroll
            for (int kw = 0; kw < 5; ++kw)
              acc[i][dy][dx] += w5[kw] * in[2 * i + dx + kw];
      }
    }
  }
  const float bv = bias[co];
#pragma unroll
  for (int i = 0; i < 8; ++i) {
    float m = fmaxf(fmaxf(acc[i][0][0], acc[i][0][1]), fmaxf(acc[i][1][0], acc[i][1][1]));
    P[((size_t)(b * 64 + co) << 10) + (ph << 5) + pq * 8 + i] = fmaxf(m + bv, 0.f);
  }
}

// ---------------- BN stats (2-stage) ----------------
__global__ __launch_bounds__(256) void bn_part_k(const float* __restrict__ P,
                                                 float* __restrict__ buf) {
  int c = blockIdx.x, s = blockIdx.y;
  float s1 = 0.f, s2 = 0.f;
  for (int i = threadIdx.x; i < 4096; i += 256) {
    int b = s * 4 + (i >> 10), p = i & 1023;
    float v = P[((size_t)(b * 64 + c) << 10) + p];
    s1 += v; s2 += v * v;
  }
#pragma unroll
  for (int o = 32; o > 0; o >>= 1) { s1 += __shfl_down(s1, o); s2 += __shfl_down(s2, o); }
  __shared__ float sh[2][4];
  int wid = threadIdx.x >> 6;
  if ((threadIdx.x & 63) == 0) { sh[0][wid] = s1; sh[1][wid] = s2; }
  __syncthreads();
  if (threadIdx.x == 0) {
    buf[c * 8 + s] = sh[0][0] + sh[0][1] + sh[0][2] + sh[0][3];
    buf[512 + c * 8 + s] = sh[1][0] + sh[1][1] + sh[1][2] + sh[1][3];
  }
}
__global__ __launch_bounds__(64) void bn_comb_k(float* __restrict__ buf) {
  int c = threadIdx.x;
  float s1 = 0.f, s2 = 0.f;
#pragma unroll
  for (int s = 0; s < 8; ++s) { s1 += buf[c * 8 + s]; s2 += buf[512 + c * 8 + s]; }
  float mean = s1 / 32768.f;
  float var = s2 / 32768.f - mean * mean;
  buf[1024 + c] = mean;
  buf[1088 + c] = rsqrtf(var + 1e-5f);
}

// ---------------- gather + BN -> PG pair + CW(slot0) ----------------
__global__ __launch_bounds__(256) void build_x0_k(const float* __restrict__ P,
                                                  const float* __restrict__ buf,
                                                  const int* __restrict__ ni,
                                                  const int* __restrict__ perm,
                                                  ushortT* __restrict__ PGh,
                                                  ushortT* __restrict__ PGl,
                                                  ushortT* __restrict__ CW0) {
  __shared__ float vals[64][33];
  __shared__ int qv[32];
  const int b = blockIdx.x >> 5, vc = blockIdx.x & 31;
  const int t = threadIdx.x;
  if (t < 32) {
    int pv = perm[vc * 32 + t];
    qv[t] = ni[2 * pv] * 32 + ni[2 * pv + 1];
  }
  __syncthreads();
  {
    int c = t & 63, vh = t >> 6;
    float mean = buf[1024 + c], rstd = buf[1088 + c];
    const float* pc = &P[((size_t)(b * 64 + c)) << 10];
#pragma unroll
    for (int j = 0; j < 8; ++j) {
      int vl = vh * 8 + j;
      vals[c][vl] = (pc[qv[vl]] - mean) * rstd;
    }
  }
  __syncthreads();
  {  // PG pair: thread (c, v-octet)
    int c = t & 63, vo = t >> 6;
    u16x8 h8, l8;
#pragma unroll
    for (int j = 0; j < 8; ++j) {
      float f = vals[c][vo * 8 + j];
      unsigned short h = f2bf(f);
      h8[j] = h; l8[j] = f2bf(f - bfu2f(h));
    }
    size_t base = ((size_t)(vc * 4 + vo) * 2048 + b * 64 + c) * 8;
    *(u16x8*)&PGh[base] = h8;
    *(u16x8*)&PGl[base] = l8;
  }
  {  // CW: thread (c-octet, v-local)
    int co = t & 7, vl = t >> 3;
    u16x8 h8;
#pragma unroll
    for (int j = 0; j < 8; ++j) h8[j] = f2bf(vals[co * 8 + j][vl]);
    *(u16x8*)&CW0[((size_t)(b * 1024 + vc * 32 + vl) * 64) + co * 8] = h8;
  }
}

// ---------------- L split fp32 -> bf16 hi/lo ----------------
__global__ __launch_bounds__(256) void lsplit_k(const float* __restrict__ L,
                                                ushortT* __restrict__ Lh,
                                                ushortT* __restrict__ Ll, int n) {
  int d = blockIdx.x * 256 + threadIdx.x;
  if (d >= n) return;
  float v = L[d];
  unsigned short h = f2bf(v);
  Lh[d] = h; Ll[d] = f2bf(v - bfu2f(h));
}

// ---------------- W prep: WA[f][kq*Cc+c] (hi/lo) ----------------
__global__ __launch_bounds__(256) void wprep_k(const float* __restrict__ W,
                                               ushortT* __restrict__ WAh,
                                               ushortT* __restrict__ WAl, int Cc, int Nf) {
  int d = blockIdx.x * 256 + threadIdx.x;
  if (d >= Nf * 16 * Cc) return;
  int c = d % Cc, kq = (d / Cc) % 16, f = d / (16 * Cc);
  float v = W[(size_t)f * (Cc * 16) + c * 16 + kq];
  unsigned short h = f2bf(v);
  WAh[d] = h; WAl[d] = f2bf(v - bfu2f(h));
}

// ---------------- Chebyshev step: MFMA, 3-product split ----------------
// MODE 0: out = L@x ; MODE 1: out = 2*(L@x) - prev (in-place over prev pair)
template <int TM, int CB, int MODE>
__global__ __launch_bounds__(256) void cheb_step_k(
    int Mld, int Kd,
    const ushortT* __restrict__ Ah, const ushortT* __restrict__ Al,
    const ushortT* __restrict__ Lbh, const ushortT* __restrict__ Lbl,
    ushortT* __restrict__ Ph, ushortT* __restrict__ Pl,
    ushortT* __restrict__ CW) {
  constexpr int FN = (TM == 64) ? 2 : 1;
  constexpr int CSH = (CB == 64) ? 6 : 7;
  __shared__ ushortT sAh[8 * TM * 8], sAl[8 * TM * 8];
  __shared__ ushortT sBh[8 * 64 * 8], sBl[8 * 64 * 8];
  const int m0 = blockIdx.x * TM, n0 = blockIdx.y * 64;
  const int t = threadIdx.x, lane = t & 63, wid = t >> 6;
  const int wm0 = (TM == 64) ? (wid >> 1) * 32 : 0;
  const int wn0 = (TM == 64) ? (wid & 1) * 32 : wid * 16;
  f32x4 acc[2][FN];
#pragma unroll
  for (int a = 0; a < 2; ++a)
#pragma unroll
    for (int c = 0; c < FN; ++c) acc[a][c] = (f32x4){0.f, 0.f, 0.f, 0.f};

  for (int k0 = 0; k0 < Kd; k0 += 64) {
    __syncthreads();
    for (int idx = t; idx < TM * 8; idx += 256) {
      int m = idx & (TM - 1), slot = idx / TM;
      size_t g = ((size_t)((k0 >> 3) + slot) * Mld + (m0 + m)) * 8;
      *(uint4*)&sAh[(slot * TM + m) * 8] = *(const uint4*)&Ah[g];
      *(uint4*)&sAl[(slot * TM + m) * 8] = *(const uint4*)&Al[g];
    }
    for (int idx = t; idx < 512; idx += 256) {
      int n = idx & 63, slot = idx >> 6;
      size_t g = (size_t)(n0 + n) * Kd + k0 + slot * 8;
      *(uint4*)&sBh[(slot * 64 + n) * 8] = *(const uint4*)&Lbh[g];
      *(uint4*)&sBl[(slot * 64 + n) * 8] = *(const uint4*)&Lbl[g];
    }
    __syncthreads();
#pragma unroll
    for (int ks = 0; ks < 2; ++ks) {
      const int srow = ks * 4 + (lane >> 4);
      const int ar = wm0 + (lane & 15);
      const int br = wn0 + (lane & 15);
      bf16x8 ah0 = *(const bf16x8*)&sAh[(srow * TM + ar) * 8];
      bf16x8 ah1 = *(const bf16x8*)&sAh[(srow * TM + ar + 16) * 8];
      bf16x8 al0 = *(const bf16x8*)&sAl[(srow * TM + ar) * 8];
      bf16x8 al1 = *(const bf16x8*)&sAl[(srow * TM + ar + 16) * 8];
      bf16x8 bh0 = *(const bf16x8*)&sBh[(srow * 64 + br) * 8];
      bf16x8 bl0 = *(const bf16x8*)&sBl[(srow * 64 + br) * 8];
      acc[0][0] = __builtin_amdgcn_mfma_f32_16x16x32_bf16(ah0, bh0, acc[0][0], 0, 0, 0);
      acc[0][0] = __builtin_amdgcn_mfma_f32_16x16x32_bf16(al0, bh0, acc[0][0], 0, 0, 0);
      acc[0][0] = __builtin_amdgcn_mfma_f32_16x16x32_bf16(ah0, bl0, acc[0][0], 0, 0, 0);
      acc[1][0] = __builtin_amdgcn_mfma_f32_16x16x32_bf16(ah1, bh0, acc[1][0], 0, 0, 0);
      acc[1][0] = __builtin_amdgcn_mfma_f32_16x16x32_bf16(al1, bh0, acc[1][0], 0, 0, 0);
      acc[1][0] = __builtin_amdgcn_mfma_f32_16x16x32_bf16(ah1, bl0, acc[1][0], 0, 0, 0);
      if constexpr (FN == 2) {
        bf16x8 bh1 = *(const bf16x8*)&sBh[(srow * 64 + br + 16) * 8];
        bf16x8 bl1 = *(const bf16x8*)&sBl[(srow * 64 + br + 16) * 8];
        acc[0][1] = __builtin_amdgcn_mfma_f32_16x16x32_bf16(ah0, bh1, acc[0][1], 0, 0, 0);
        acc[0][1] = __builtin_amdgcn_mfma_f32_16x16x32_bf16(al0, bh1, acc[0][1], 0, 0, 0);
        acc[0][1] = __builtin_amdgcn_mfma_f32_16x16x32_bf16(ah0, bl1, acc[0][1], 0, 0, 0);
        acc[1][1] = __builtin_amdgcn_mfma_f32_16x16x32_bf16(ah1, bh1, acc[1][1], 0, 0, 0);
        acc[1][1] = __builtin_amdgcn_mfma_f32_16x16x32_bf16(al1, bh1, acc[1][1], 0, 0, 0);
        acc[1][1] = __builtin_amdgcn_mfma_f32_16x16x32_bf16(ah1, bl1, acc[1][1], 0, 0, 0);
      }
    }
  }
#pragma unroll
  for (int fm = 0; fm < 2; ++fm)
#pragma unroll
    for (int fn = 0; fn < FN; ++fn) {
      const int gmb = m0 + wm0 + fm * 16 + (lane >> 4) * 4;
      const int gn = n0 + wn0 + fn * 16 + (lane & 15);
      unsigned short cw4[4];
#pragma unroll
      for (int j = 0; j < 4; ++j) {
        int gm = gmb + j;
        size_t g = ((size_t)(gn >> 3) * Mld + gm) * 8 + (gn & 7);
        float d = acc[fm][fn][j];
        float nv;
        if (MODE == 0) nv = d;
        else nv = 2.f * d - (bfu2f(Ph[g]) + bfu2f(Pl[g]));
        unsigned short h = f2bf(nv);
        Ph[g] = h;
        Pl[g] = f2bf(nv - bfu2f(h));
        cw4[j] = h;
      }
      const int c0 = gmb & (CB - 1), bidx = gmb >> CSH;
      size_t cbase = ((size_t)bidx * Kd + gn) * CB + c0;
      uint2 u;
      u.x = (unsigned)cw4[0] | ((unsigned)cw4[1] << 16);
      u.y = (unsigned)cw4[2] | ((unsigned)cw4[3] << 16);
      *(uint2*)&CW[cbase] = u;
    }
}

// ---------------- weight apply: MFMA, W hi/lo x X hi ----------------
// OUT[f][n] (+)= sum over 4 states, Cc chans
template <int Cc, int MODE>
__global__ __launch_bounds__(256) void wapply_k(
    int NN, int ldw, int koff,
    const ushortT* __restrict__ WAh, const ushortT* __restrict__ WAl,
    const ushortT* __restrict__ cw0, const ushortT* __restrict__ cw1,
    const ushortT* __restrict__ cw2, const ushortT* __restrict__ cw3,
    float* __restrict__ OUT) {
  constexpr int NT = 4 * Cc / 64;
  __shared__ ushortT sWh[8 * 64 * 8], sWl[8 * 64 * 8], sX[8 * 64 * 8];
  const int m0 = blockIdx.x * 64, n0 = blockIdx.y * 64;
  const int t = threadIdx.x, lane = t & 63, wid = t >> 6;
  const int wm0 = (wid >> 1) * 32, wn0 = (wid & 1) * 32;
  f32x4 acc[2][2];
#pragma unroll
  for (int a = 0; a < 2; ++a)
#pragma unroll
    for (int c = 0; c < 2; ++c) acc[a][c] = (f32x4){0.f, 0.f, 0.f, 0.f};

#pragma unroll
  for (int kt = 0; kt < NT; ++kt) {
    const int s = (Cc == 64) ? kt : (kt >> 1);
    const int coff = (Cc == 64) ? 0 : ((kt & 1) * 64);
    const ushortT* cw = (s == 0) ? cw0 : (s == 1) ? cw1 : (s == 2) ? cw2 : cw3;
    __syncthreads();
    for (int idx = t; idx < 512; idx += 256) {
      int m = idx & 63, oct = idx >> 6;
      size_t g = (size_t)(m0 + m) * ldw + koff + kt * 64 + oct * 8;
      *(uint4*)&sWh[(oct * 64 + m) * 8] = *(const uint4*)&WAh[g];
      *(uint4*)&sWl[(oct * 64 + m) * 8] = *(const uint4*)&WAl[g];
    }
    for (int idx = t; idx < 512; idx += 256) {
      int n = idx & 63, oct = idx >> 6;
      size_t g = (size_t)(n0 + n) * Cc + coff + oct * 8;
      *(uint4*)&sX[(oct * 64 + n) * 8] = *(const uint4*)&cw[g];
    }
    __syncthreads();
#pragma unroll
    for (int ks = 0; ks < 2; ++ks) {
      const int srow = ks * 4 + (lane >> 4);
      const int am = wm0 + (lane & 15);
      const int bn = wn0 + (lane & 15);
      bf16x8 wh0 = *(const bf16x8*)&sWh[(srow * 64 + am) * 8];
      bf16x8 wh1 = *(const bf16x8*)&sWh[(srow * 64 + am + 16) * 8];
      bf16x8 wl0 = *(const bf16x8*)&sWl[(srow * 64 + am) * 8];
      bf16x8 wl1 = *(const bf16x8*)&sWl[(srow * 64 + am + 16) * 8];
      bf16x8 x0 = *(const bf16x8*)&sX[(srow * 64 + bn) * 8];
      bf16x8 x1 = *(const bf16x8*)&sX[(srow * 64 + bn + 16) * 8];
      acc[0][0] = __builtin_amdgcn_mfma_f32_16x16x32_bf16(wh0, x0, acc[0][0], 0, 0, 0);
      acc[0][0] = __builtin_amdgcn_mfma_f32_16x16x32_bf16(wl0, x0, acc[0][0], 0, 0, 0);
      acc[0][1] = __builtin_amdgcn_mfma_f32_16x16x32_bf16(wh0, x1, acc[0][1], 0, 0, 0);
      acc[0][1] = __builtin_amdgcn_mfma_f32_16x16x32_bf16(wl0, x1, acc[0][1], 0, 0, 0);
      acc[1][0] = __builtin_amdgcn_mfma_f32_16x16x32_bf16(wh1, x0, acc[1][0], 0, 0, 0);
      acc[1][0] = __builtin_amdgcn_mfma_f32_16x16x32_bf16(wl1, x0, acc[1][0], 0, 0, 0);
      acc[1][1] = __builtin_amdgcn_mfma_f32_16x16x32_bf16(wh1, x1, acc[1][1], 0, 0, 0);
      acc[1][1] = __builtin_amdgcn_mfma_f32_16x16x32_bf16(wl1, x1, acc[1][1], 0, 0, 0);
    }
  }
#pragma unroll
  for (int fm = 0; fm < 2; ++fm)
#pragma unroll
    for (int fn = 0; fn < 2; ++fn)
#pragma unroll
      for (int j = 0; j < 4; ++j) {
        int gm = m0 + wm0 + fm * 16 + (lane >> 4) * 4 + j;
        int gn = n0 + wn0 + fn * 16 + (lane & 15);
        size_t g = (size_t)gm * NN + gn;
        if (MODE == 0) OUT[g] = acc[fm][fn][j];
        else OUT[g] += acc[fm][fn][j];
      }
}

// ---------------- gc1 epilogue -> PG2 pair + CW2 slot0 ----------------
__global__ __launch_bounds__(256) void relu_pool1_k(const float* __restrict__ OUT1T,
                                                    const float* __restrict__ b2,
                                                    ushortT* __restrict__ PG2h,
                                                    ushortT* __restrict__ PG2l,
                                                    ushortT* __restrict__ CW0) {
  __shared__ float sval[128][9];
  const int b = blockIdx.x >> 5, vc = blockIdx.x & 31;
  const int t = threadIdx.x;
  {
    int f = t & 127, h = t >> 7;
    float bb = b2[f];
    const float* src = &OUT1T[(size_t)f * 32768 + b * 1024 + vc * 32];
#pragma unroll
    for (int i = 0; i < 4; ++i) {
      int v2l = h * 4 + i;
      float4 r = *(const float4*)&src[v2l * 4];
      float m = fmaxf(fmaxf(r.x, r.y), fmaxf(r.z, r.w));
      sval[f][v2l] = fmaxf(m + bb, 0.f);
    }
  }
  __syncthreads();
  if (t < 128) {
    int f = t;
    u16x8 h8, l8;
#pragma unroll
    for (int j = 0; j < 8; ++j) {
      float v = sval[f][j];
      unsigned short h = f2bf(v);
      h8[j] = h; l8[j] = f2bf(v - bfu2f(h));
    }
    size_t base = ((size_t)vc * 4096 + b * 128 + f) * 8;
    *(u16x8*)&PG2h[base] = h8;
    *(u16x8*)&PG2l[base] = l8;
  } else {
    int q = t - 128;
    int co = q & 15, v2l = q >> 4;
    u16x8 h8;
#pragma unroll
    for (int j = 0; j < 8; ++j) h8[j] = f2bf(sval[co * 8 + j][v2l]);
    *(u16x8*)&CW0[((size_t)(b * 256 + vc * 8 + v2l) * 128) + co * 8] = h8;
  }
}

// ---------------- gc2 epilogue -> At[b][f*64+v3] ----------------
__global__ __launch_bounds__(256) void relu_pool2_k(const float* __restrict__ OUT2T,
                                                    const float* __restrict__ b3,
                                                    float* __restrict__ At) {
  int n = blockIdx.x * 256 + threadIdx.x;  // 524288
  int v3 = n & 63, f = (n >> 6) & 255, b = n >> 14;
  float4 r = *(const float4*)&OUT2T[((size_t)f * 32 + b) * 256 + v3 * 4];
  float m = fmaxf(fmaxf(r.x, r.y), fmaxf(r.z, r.w));
  At[(size_t)b * FC1_IN + f * 64 + v3] = fmaxf(m + b3[f], 0.f);
}

// ---------------- fc1: 1024-block split-K ----------------
__global__ __launch_bounds__(256) void fc1_part_k(const float* __restrict__ At,
                                                  const float* __restrict__ W1,
                                                  float* __restrict__ part) {
  const int jt = blockIdx.x, ks = blockIdx.y;
  const int tid = threadIdx.x;
  const int b = tid & 31, jg = tid >> 5;
  const int j0 = jt * 32 + jg * 4;
  const int k0 = ks * 256;
  float acc[4] = {0.f, 0.f, 0.f, 0.f};
  const float* a = At + (size_t)b * FC1_IN + k0;
#pragma unroll 4
  for (int k = 0; k < 256; k += 4) {
    float4 a4 = *reinterpret_cast<const float4*>(a + k);
#pragma unroll
    for (int jj = 0; jj < 4; ++jj) {
      const float4 w4 = *reinterpret_cast<const float4*>(&W1[(size_t)(j0 + jj) * FC1_IN + k0 + k]);
      acc[jj] += a4.x * w4.x + a4.y * w4.y + a4.z * w4.z + a4.w * w4.w;
    }
  }
#pragma unroll
  for (int jj = 0; jj < 4; ++jj) part[((size_t)ks * 32 + b) * 512 + j0 + jj] = acc[jj];
}

__global__ __launch_bounds__(256) void fc1_combine_k(const float* __restrict__ part,
                                                     const float* __restrict__ b1,
                                                     float* __restrict__ h) {
  int n = blockIdx.x * 256 + threadIdx.x;  // 16384
  int b = n >> 9, j = n & 511;
  float s = b1[j];
#pragma unroll
  for (int ks = 0; ks < 64; ++ks) s += part[((size_t)ks * 32 + b) * 512 + j];
  h[n] = fmaxf(s, 0.f);
}

__global__ __launch_bounds__(64) void fc2_k(const float* __restrict__ h,
                                            const float* __restrict__ W2,
                                            const float* __restrict__ b2f,
                                            float* __restrict__ out) {
  int n = blockIdx.x * 64 + threadIdx.x;  // 320
  if (n >= 320) return;
  int b = n / 10, o = n % 10;
  float s = b2f[o];
  const float* hp = h + b * 512;
  const float* wp = W2 + o * 512;
  for (int j = 0; j < 512; ++j) s += hp[j] * wp[j];
  out[n] = s;
}

// ---------------- launch ----------------
extern "C" void kernel_launch(void* const* d_in, const int* in_sizes, int n_in,
                              void* d_out, int out_size, void* d_ws, size_t ws_size,
                              hipStream_t stream) {
  const float* x      = (const float*)d_in[0];
  const float* conv1w = (const float*)d_in[1];
  const float* conv1b = (const float*)d_in[2];
  const float* L1     = (const float*)d_in[3];
  const float* L2     = (const float*)d_in[4];
  const int*   ni     = (const int*)d_in[5];
  const int*   perm   = (const int*)d_in[6];
  const float* k2w    = (const float*)d_in[7];
  const float* k2b    = (const float*)d_in[8];
  const float* k3w    = (const float*)d_in[9];
  const float* k3b    = (const float*)d_in[10];
  const float* fc1w   = (const float*)d_in[11];
  const float* fc1b   = (const float*)d_in[12];
  const float* fc2w   = (const float*)d_in[13];
  const float* fc2b   = (const float*)d_in[14];
  float* out = (float*)d_out;

  char* ws = (char*)d_ws;
  const size_t MB = 1024 * 1024;
  // phase A/B
  float*   P     = (float*)(ws + 0);                 // 8MB
  ushortT* cw1[4] = {(ushortT*)(ws + 8 * MB), (ushortT*)(ws + 12 * MB),
                     (ushortT*)(ws + 16 * MB), (ushortT*)(ws + 20 * MB)};
  ushortT* pgAh = (ushortT*)(ws + 24 * MB);
  ushortT* pgAl = (ushortT*)(ws + 28 * MB);
  ushortT* pgBh = (ushortT*)(ws + 32 * MB);
  ushortT* pgBl = (ushortT*)(ws + 36 * MB);
  float*   OUT1T = (float*)(ws + 40 * MB);           // 17MB
  ushortT* L1h  = (ushortT*)(ws + 57 * MB);
  ushortT* L1l  = (ushortT*)(ws + 59 * MB);
  ushortT* WA1h = (ushortT*)(ws + 61 * MB);          // 256KB
  ushortT* WA1l = (ushortT*)(ws + 61 * MB + 262144);
  float*   BNB  = (float*)(ws + 61 * MB + 524288);   // ~5KB
  // phase C/D overlays
  ushortT* cw2[4] = {(ushortT*)(ws + 0), (ushortT*)(ws + 2 * MB),
                     (ushortT*)(ws + 4 * MB), (ushortT*)(ws + 6 * MB)};
  ushortT* pg2Ah = (ushortT*)(ws + 8 * MB);
  ushortT* pg2Al = (ushortT*)(ws + 10 * MB);
  ushortT* pg2Bh = (ushortT*)(ws + 12 * MB);
  ushortT* pg2Bl = (ushortT*)(ws + 14 * MB);
  float*   OUT2T = (float*)(ws + 16 * MB);           // 8.4MB
  ushortT* L2h  = (ushortT*)(ws + 25 * MB);
  ushortT* L2l  = (ushortT*)(ws + 25 * MB + 131072);
  ushortT* WA2h = (ushortT*)(ws + 26 * MB);          // 1MB
  ushortT* WA2l = (ushortT*)(ws + 27 * MB);
  float*   At   = (float*)(ws + 28 * MB);            // 2MB
  float*   PART = (float*)(ws + 30 * MB);            // 4MB
  float*   H    = (float*)(ws + 34 * MB);            // 64KB

  // ---- phase A ----
  conv_pool_k<<<1024, 256, 0, stream>>>(x, conv1w, conv1b, P);
  bn_part_k<<<dim3(64, 8), 256, 0, stream>>>(P, BNB);
  bn_comb_k<<<1, 64, 0, stream>>>(BNB);
  lsplit_k<<<4096, 256, 0, stream>>>(L1, L1h, L1l, 1024 * 1024);
  wprep_k<<<512, 256, 0, stream>>>(k2w, WA1h, WA1l, 64, 128);
  build_x0_k<<<1024, 256, 0, stream>>>(P, BNB, ni, perm, pgAh, pgAl, cw1[0]);

  // ---- phase B: gc1 ----
  cheb_step_k<64, 64, 0><<<dim3(32, 16), 256, 0, stream>>>(2048, 1024, pgAh, pgAl, L1h, L1l, pgBh, pgBl, cw1[1]);
  for (int k = 2; k < 16; ++k) {
    ushortT *ah, *al, *oh, *ol;
    if (k & 1) { ah = pgAh; al = pgAl; oh = pgBh; ol = pgBl; }
    else       { ah = pgBh; al = pgBl; oh = pgAh; ol = pgAl; }
    cheb_step_k<64, 64, 1><<<dim3(32, 16), 256, 0, stream>>>(2048, 1024, ah, al, L1h, L1l, oh, ol, cw1[k & 3]);
    if ((k & 3) == 3) {
      int kb = k >> 2;
      if (kb == 0)
        wapply_k<64, 0><<<dim3(2, 512), 256, 0, stream>>>(32768, 1024, 0, WA1h, WA1l,
                                                          cw1[0], cw1[1], cw1[2], cw1[3], OUT1T);
      else
        wapply_k<64, 1><<<dim3(2, 512), 256, 0, stream>>>(32768, 1024, kb * 256, WA1h, WA1l,
                                                          cw1[0], cw1[1], cw1[2], cw1[3], OUT1T);
    }
  }

  // ---- phase C: gc2 ----
  relu_pool1_k<<<1024, 256, 0, stream>>>(OUT1T, k2b, pg2Ah, pg2Al, cw2[0]);
  lsplit_k<<<256, 256, 0, stream>>>(L2, L2h, L2l, 65536);
  wprep_k<<<2048, 256, 0, stream>>>(k3w, WA2h, WA2l, 128, 256);

  cheb_step_k<32, 128, 0><<<dim3(128, 4), 256, 0, stream>>>(4096, 256, pg2Ah, pg2Al, L2h, L2l, pg2Bh, pg2Bl, cw2[1]);
  for (int k = 2; k < 16; ++k) {
    ushortT *ah, *al, *oh, *ol;
    if (k & 1) { ah = pg2Ah; al = pg2Al; oh = pg2Bh; ol = pg2Bl; }
    else       { ah = pg2Bh; al = pg2Bl; oh = pg2Ah; ol = pg2Al; }
    cheb_step_k<32, 128, 1><<<dim3(128, 4), 256, 0, stream>>>(4096, 256, ah, al, L2h, L2l, oh, ol, cw2[k & 3]);
    if ((k & 3) == 3) {
      int kb = k >> 2;
      if (kb == 0)
        wapply_k<128, 0><<<dim3(4, 128), 256, 0, stream>>>(8192, 2048, 0, WA2h, WA2l,
                                                           cw2[0], cw2[1], cw2[2], cw2[3], OUT2T);
      else
        wapply_k<128, 1><<<dim3(4, 128), 256, 0, stream>>>(8192, 2048, kb * 512, WA2h, WA2l,
                                                           cw2[0], cw2[1], cw2[2], cw2[3], OUT2T);
    }
  }

  // ---- phase D: fc ----
  relu_pool2_k<<<2048, 256, 0, stream>>>(OUT2T, k3b, At);
  fc1_part_k<<<dim3(16, 64), 256, 0, stream>>>(At, fc1w, PART);
  fc1_combine_k<<<64, 256, 0, stream>>>(PART, fc1b, H);
  fc2_k<<<5, 64, 0, stream>>>(H, fc2w, fc2b, out);
}